// Round 1
// baseline (2011.537 us; speedup 1.0000x reference)
//
#include <hip/hip_runtime.h>
#include <math.h>

#define BDIM 2
#define CDIM 256
#define HDIM 128
#define WDIM 128
#define HW (HDIM*WDIM)
#define NPIX (BDIM*HW)

__device__ __forceinline__ float geluf(float x){
  return 0.5f*x*(1.f+erff(x*0.70710678118654752f));
}

// ---------------- NCHW -> NHWC transpose ----------------
__global__ __launch_bounds__(256) void k_transpose(const float* __restrict__ in, float* __restrict__ out){
  __shared__ float tile[32][33];
  int b = blockIdx.z;
  int c0 = blockIdx.y*32;
  int p0 = blockIdx.x*32;
  int tx = threadIdx.x, ty = threadIdx.y;
  const float* src = in + (size_t)b*CDIM*HW;
  float* dst = out + (size_t)b*HW*CDIM;
  #pragma unroll
  for (int i=ty;i<32;i+=8) tile[i][tx] = src[(size_t)(c0+i)*HW + p0+tx];
  __syncthreads();
  #pragma unroll
  for (int i=ty;i<32;i+=8) dst[(size_t)(p0+i)*CDIM + c0+tx] = tile[tx][i];
}

// ---------------- offset conv: 3x3, Cin=256 -> 18, pad=dil ----------------
// block = 256 threads (thread = channel), 32 pixels (one row chunk) per block.
// weights staged in LDS in chunks of 6 output channels.
template<int DIL>
__global__ __launch_bounds__(256) void k_offconv(const float* __restrict__ xt,
        const float* __restrict__ woff, float* __restrict__ off){
  __shared__ float wsh[6*CDIM*9];   // 55296 B
  __shared__ float red[24];
  const int t = threadIdx.x;
  const int lane = t & 63, wid = t >> 6;
  const int p0 = blockIdx.x * 32;
  const int b  = p0 / HW;
  const int prow = p0 % HW;
  const int hh = prow / WDIM;
  const int w0 = prow % WDIM;
  for (int oc = 0; oc < 3; ++oc) {
    for (int i = t; i < 6*CDIM*9; i += 256) wsh[i] = woff[(size_t)oc*6*CDIM*9 + i];
    __syncthreads();
    for (int q = 0; q < 32; ++q) {
      const int ww = w0 + q;
      float tap[9];
      #pragma unroll
      for (int ky=0; ky<3; ++ky)
        #pragma unroll
        for (int kx=0; kx<3; ++kx) {
          int y = hh + (ky-1)*DIL, x = ww + (kx-1)*DIL;
          float v = 0.f;
          if ((unsigned)y < HDIM && (unsigned)x < WDIM)
            v = xt[((size_t)b*HW + (size_t)y*WDIM + x)*CDIM + t];
          tap[ky*3+kx] = v;
        }
      float a[6];
      #pragma unroll
      for (int o=0;o<6;++o) {
        const float* wr = &wsh[(o*CDIM + t)*9];
        float s = 0.f;
        #pragma unroll
        for (int k=0;k<9;++k) s = fmaf(wr[k], tap[k], s);
        a[o] = s;
      }
      #pragma unroll
      for (int o=0;o<6;++o)
        #pragma unroll
        for (int m=32;m;m>>=1) a[o] += __shfl_xor(a[o], m);
      if (lane == 0) {
        #pragma unroll
        for (int o=0;o<6;++o) red[wid*6+o] = a[o];
      }
      __syncthreads();
      if (t < 6) {
        float s = red[t] + red[6+t] + red[12+t] + red[18+t];
        off[(size_t)(p0+q)*18 + oc*6 + t] = s;
      }
      __syncthreads();
    }
  }
}

// ---------------- 1x1 conv: acc = conv_w @ x + conv_b (NHWC) ----------------
__global__ __launch_bounds__(256) void k_conv1x1(const float* __restrict__ xt,
     const float* __restrict__ wc, const float* __restrict__ bc, float* __restrict__ acc){
  __shared__ float xs[16*CDIM];
  int t = threadIdx.x;
  size_t p0 = (size_t)blockIdx.x * 16;
  for (int i=t;i<16*CDIM;i+=256) xs[i] = xt[p0*CDIM + i];
  __syncthreads();
  float r[16];
  #pragma unroll
  for (int q=0;q<16;++q) r[q]=0.f;
  const float* wr = &wc[(size_t)t*CDIM];
  for (int k=0;k<CDIM;k+=4) {
    float4 w4 = *(const float4*)&wr[k];
    #pragma unroll
    for (int q=0;q<16;++q) {
      float4 x4 = *(const float4*)&xs[q*CDIM+k];
      r[q] = fmaf(w4.x,x4.x, fmaf(w4.y,x4.y, fmaf(w4.z,x4.z, fmaf(w4.w,x4.w, r[q]))));
    }
  }
  float bb = bc[t];
  #pragma unroll
  for (int q=0;q<16;++q) acc[(p0+q)*CDIM + t] = r[q] + bb;
}

// ------- deformable depthwise 3x3 + LayerNorm2d + GELU, accumulate into acc -------
template<int DIL>
__global__ __launch_bounds__(256) void k_deform(const float* __restrict__ xt,
    const float* __restrict__ off, const float* __restrict__ dw,
    const float* __restrict__ lw, const float* __restrict__ lb,
    float* __restrict__ acc){
  __shared__ float offs[18];
  __shared__ float red[8];
  int t = threadIdx.x, lane = t&63, wid = t>>6;
  size_t gp = blockIdx.x;
  int b  = (int)(gp >> 14);
  int p  = (int)(gp & (HW-1));
  int hh = p >> 7, ww = p & (WDIM-1);
  if (t < 18) offs[t] = off[gp*18 + t];
  __syncthreads();
  const float* xb = xt + (size_t)b*HW*CDIM;
  float d = 0.f;
  #pragma unroll
  for (int k=0;k<9;++k) {
    int ky = k/3, kx = k%3;
    float py = (float)(hh + (ky-1)*DIL) + offs[2*k];
    float px = (float)(ww + (kx-1)*DIL) + offs[2*k+1];
    float y0 = floorf(py), x0 = floorf(px);
    float fy = py - y0, fx = px - x0;
    int iy = (int)y0, ix = (int)x0;
    float s = 0.f;
    #pragma unroll
    for (int dy=0; dy<2; ++dy)
      #pragma unroll
      for (int dx=0; dx<2; ++dx) {
        int yy = iy+dy, xx = ix+dx;
        float wgt = (dy? fy : 1.f-fy) * (dx? fx : 1.f-fx);
        if ((unsigned)yy < HDIM && (unsigned)xx < WDIM)
          s = fmaf(wgt, xb[((size_t)yy*WDIM+xx)*CDIM + t], s);
      }
    d = fmaf(dw[t*9+k], s, d);
  }
  // LayerNorm over channels at this pixel
  float sum = d, sq = d*d;
  #pragma unroll
  for (int m=32;m;m>>=1){ sum += __shfl_xor(sum,m); sq += __shfl_xor(sq,m); }
  if (lane==0){ red[wid]=sum; red[4+wid]=sq; }
  __syncthreads();
  sum = red[0]+red[1]+red[2]+red[3];
  sq  = red[4]+red[5]+red[6]+red[7];
  float u = sum*(1.f/CDIM);
  float var = sq*(1.f/CDIM) - u*u;
  float xn = (d-u)*rsqrtf(var + 1e-6f);
  float y  = lw[t]*xn + lb[t];
  acc[gp*CDIM + t] += geluf(y);
}

// ---------------- per-pixel channel LayerNorm ----------------
__global__ __launch_bounds__(256) void k_ln(const float* __restrict__ in,
    const float* __restrict__ w, const float* __restrict__ bsrc, float* __restrict__ outb){
  __shared__ float red[8];
  int t = threadIdx.x, lane = t&63, wid = t>>6;
  size_t gp = blockIdx.x;
  float v = in[gp*CDIM + t];
  float sum = v, sq = v*v;
  #pragma unroll
  for (int m=32;m;m>>=1){ sum += __shfl_xor(sum,m); sq += __shfl_xor(sq,m); }
  if (lane==0){ red[wid]=sum; red[4+wid]=sq; }
  __syncthreads();
  sum = red[0]+red[1]+red[2]+red[3];
  sq  = red[4]+red[5]+red[6]+red[7];
  float u = sum*(1.f/CDIM);
  float var = sq*(1.f/CDIM) - u*u;
  outb[gp*CDIM + t] = w[t]*((v-u)*rsqrtf(var+1e-6f)) + bsrc[t];
}

// ------- fused MLP (256->512 gelu ->256) + residual + LN2 + NCHW write -------
__global__ __launch_bounds__(256) void k_mlp(const float* __restrict__ out1,
    const float* __restrict__ w1, const float* __restrict__ b1,
    const float* __restrict__ w2, const float* __restrict__ b2,
    const float* __restrict__ n2w, const float* __restrict__ n2b,
    float* __restrict__ dout){
  __shared__ float xs[16*CDIM];   // 16 KB
  __shared__ float hs[16*512];    // 32 KB
  __shared__ float red[8];
  int t = threadIdx.x, lane = t&63, wid = t>>6;
  size_t p0 = (size_t)blockIdx.x * 16;
  for (int i=t;i<16*CDIM;i+=256) xs[i] = out1[p0*CDIM + i];
  __syncthreads();
  // phase 1: hidden = gelu(out1 @ W1^T + b1)
  for (int jj=0;jj<2;++jj){
    int j = t + jj*256;
    const float* wr = &w1[(size_t)j*CDIM];
    float r[16];
    #pragma unroll
    for (int q=0;q<16;++q) r[q]=0.f;
    for (int k=0;k<CDIM;k+=4){
      float4 w4 = *(const float4*)&wr[k];
      #pragma unroll
      for (int q=0;q<16;++q){
        float4 x4 = *(const float4*)&xs[q*CDIM+k];
        r[q] = fmaf(w4.x,x4.x, fmaf(w4.y,x4.y, fmaf(w4.z,x4.z, fmaf(w4.w,x4.w, r[q]))));
      }
    }
    float bj = b1[j];
    #pragma unroll
    for (int q=0;q<16;++q) hs[q*512+j] = geluf(r[q]+bj);
  }
  __syncthreads();
  // phase 2: y = hidden @ W2^T + b2 + residual
  const float* wr2 = &w2[(size_t)t*512];
  float z[16];
  #pragma unroll
  for (int q=0;q<16;++q) z[q]=0.f;
  for (int k=0;k<512;k+=4){
    float4 w4 = *(const float4*)&wr2[k];
    #pragma unroll
    for (int q=0;q<16;++q){
      float4 h4 = *(const float4*)&hs[q*512+k];
      z[q] = fmaf(w4.x,h4.x, fmaf(w4.y,h4.y, fmaf(w4.z,h4.z, fmaf(w4.w,h4.w, z[q]))));
    }
  }
  float bb = b2[t];
  #pragma unroll
  for (int q=0;q<16;++q) z[q] += bb + xs[q*CDIM+t];
  // LN2 per pixel + write NCHW
  float res[16];
  float nw = n2w[t], nb = n2b[t];
  #pragma unroll
  for (int q=0;q<16;++q){
    float sum = z[q], sq = z[q]*z[q];
    #pragma unroll
    for (int m=32;m;m>>=1){ sum += __shfl_xor(sum,m); sq += __shfl_xor(sq,m); }
    if (lane==0){ red[wid]=sum; red[4+wid]=sq; }
    __syncthreads();
    float su  = red[0]+red[1]+red[2]+red[3];
    float sqq = red[4]+red[5]+red[6]+red[7];
    __syncthreads();
    float u = su*(1.f/CDIM);
    float var = sqq*(1.f/CDIM) - u*u;
    res[q] = nw*((z[q]-u)*rsqrtf(var+1e-6f)) + nb;
  }
  int b = (int)(p0/HW);
  size_t prow0 = p0 - (size_t)b*HW;
  float* ob = dout + ((size_t)(b*CDIM + t))*HW + prow0;
  #pragma unroll
  for (int q4=0;q4<4;++q4){
    float4 v; v.x=res[q4*4]; v.y=res[q4*4+1]; v.z=res[q4*4+2]; v.w=res[q4*4+3];
    *(float4*)&ob[q4*4] = v;
  }
}

extern "C" void kernel_launch(void* const* d_in, const int* in_sizes, int n_in,
                              void* d_out, int out_size, void* d_ws, size_t ws_size,
                              hipStream_t stream){
  const float* x = (const float*)d_in[0];
  const float* off_w[3] = {(const float*)d_in[1],(const float*)d_in[5],(const float*)d_in[9]};
  const float* def_w[3] = {(const float*)d_in[2],(const float*)d_in[6],(const float*)d_in[10]};
  const float* bw[3]    = {(const float*)d_in[3],(const float*)d_in[7],(const float*)d_in[11]};
  const float* bbr[3]   = {(const float*)d_in[4],(const float*)d_in[8],(const float*)d_in[12]};
  const float* conv_w = (const float*)d_in[13];
  const float* conv_b = (const float*)d_in[14];
  const float* n1w = (const float*)d_in[15];
  const float* n1b = (const float*)d_in[16];
  const float* n2w = (const float*)d_in[17];
  const float* n2b = (const float*)d_in[18];
  const float* w1  = (const float*)d_in[19];
  const float* b1  = (const float*)d_in[20];
  const float* w2  = (const float*)d_in[21];
  const float* b2  = (const float*)d_in[22];

  float* ws  = (float*)d_ws;
  float* xt   = ws;                                  // 8388608 floats
  float* off0 = xt  + (size_t)NPIX*CDIM;             // 589824 each
  float* off1 = off0 + (size_t)NPIX*18;
  float* off2 = off1 + (size_t)NPIX*18;
  float* out1 = off2 + (size_t)NPIX*18;              // 8388608 floats
  float* acc  = (float*)d_out;                       // d_out doubles as scratch accumulator

  k_transpose<<<dim3(HW/32, CDIM/32, BDIM), dim3(32,8), 0, stream>>>(x, xt);
  k_offconv<1> <<<NPIX/32, 256, 0, stream>>>(xt, off_w[0], off0);
  k_offconv<9> <<<NPIX/32, 256, 0, stream>>>(xt, off_w[1], off1);
  k_offconv<12><<<NPIX/32, 256, 0, stream>>>(xt, off_w[2], off2);
  k_conv1x1<<<NPIX/16, 256, 0, stream>>>(xt, conv_w, conv_b, acc);
  k_deform<1> <<<NPIX, 256, 0, stream>>>(xt, off0, def_w[0], bw[0], bbr[0], acc);
  k_deform<9> <<<NPIX, 256, 0, stream>>>(xt, off1, def_w[1], bw[1], bbr[1], acc);
  k_deform<12><<<NPIX, 256, 0, stream>>>(xt, off2, def_w[2], bw[2], bbr[2], acc);
  k_ln<<<NPIX, 256, 0, stream>>>(acc, n1w, n1b, out1);
  k_mlp<<<NPIX/16, 256, 0, stream>>>(out1, w1, b1, w2, b2, n2w, n2b, (float*)d_out);
}

// Round 2
// 732.236 us; speedup vs baseline: 2.7471x; 2.7471x over previous
//
#include <hip/hip_runtime.h>
#include <math.h>

#define BDIM 2
#define CDIM 256
#define HDIM 128
#define WDIM 128
#define HW (HDIM*WDIM)
#define NPIX (BDIM*HW)

typedef float f32x4 __attribute__((ext_vector_type(4)));
typedef short bf16x8 __attribute__((ext_vector_type(8)));
typedef short bf16x4 __attribute__((ext_vector_type(4)));

__device__ __forceinline__ float geluf(float x){
  return 0.5f*x*(1.f+erff(x*0.70710678118654752f));
}
__device__ __forceinline__ unsigned short f2bf(float f){
  union{float f;unsigned u;}v; v.f=f;
  unsigned r=(v.u + 0x7FFFu + ((v.u>>16)&1u))>>16; return (unsigned short)r;
}
__device__ __forceinline__ float bf2f(unsigned short h){
  union{unsigned u;float f;}v; v.u=((unsigned)h)<<16; return v.f;
}

// ---------------- NCHW fp32 -> NHWC bf16 ----------------
__global__ __launch_bounds__(256) void k_transpose(const float* __restrict__ in,
                                                   unsigned short* __restrict__ out){
  __shared__ float tile[32][33];
  int b = blockIdx.z;
  int c0 = blockIdx.y*32;
  int p0 = blockIdx.x*32;
  int tx = threadIdx.x, ty = threadIdx.y;
  const float* src = in + (size_t)b*CDIM*HW;
  unsigned short* dst = out + (size_t)b*HW*CDIM;
  #pragma unroll
  for (int i=ty;i<32;i+=8) tile[i][tx] = src[(size_t)(c0+i)*HW + p0+tx];
  __syncthreads();
  #pragma unroll
  for (int i=ty;i<32;i+=8) dst[(size_t)(p0+i)*CDIM + c0+tx] = f2bf(tile[tx][i]);
}

// ---------------- weight packers: fragment-linear bf16 ----------------
// layout [J][ks][lane64][r8]: j=J*16+(l&15), k=ks*32+(l>>4)*8+r
__global__ void k_pack_w(const float* __restrict__ src, unsigned short* __restrict__ dst,
                         int ksn, int K, int total){
  for (int i=blockIdx.x*256+threadIdx.x; i<total; i+=gridDim.x*256){
    int r=i&7, l=(i>>3)&63, ks=(i>>9)%ksn, J=i/(ksn*512);
    int j=J*16+(l&15), k=ks*32+((l>>4)<<3)+r;
    dst[i]=f2bf(src[(size_t)j*K+k]);
  }
}
// offset-conv weights: M=18 padded to 32, K=2304 (tap-major: k = tap*256+ch)
__global__ void k_pack_off(const float* __restrict__ src, unsigned short* __restrict__ dst){
  const int total=2*72*512;
  for (int i=blockIdx.x*256+threadIdx.x; i<total; i+=gridDim.x*256){
    int r=i&7, l=(i>>3)&63, ks=(i>>9)%72, J=i/(72*512);
    int oc=J*16+(l&15), k=ks*32+((l>>4)<<3)+r;
    int tap=k>>8, ch=k&255;
    float v = (oc<18) ? src[((size_t)(oc*256+ch)*3 + tap/3)*3 + (tap%3)] : 0.f;
    dst[i]=f2bf(v);
  }
}

// ---------------- offset conv via MFMA: D[oc][pix] = Woff . T^T ----------------
// block: 32 pixels (one row segment), 4 waves split K (72 ksteps)
template<int DIL>
__global__ __launch_bounds__(256) void k_offconv(const unsigned short* __restrict__ xtb,
    const unsigned short* __restrict__ wp, float* __restrict__ off){
  __shared__ float part[4*2*2*64*4];   // 16KB
  int t=threadIdx.x, l=t&63, wv=t>>6, q=l>>4;
  int p0=blockIdx.x*32;
  int b=p0>>14, prow=p0&(HW-1);
  int hh=prow>>7, w0=prow&(WDIM-1);
  const unsigned short* xb = xtb + (size_t)b*HW*CDIM;
  f32x4 acc[2][2];
  #pragma unroll
  for(int mi=0;mi<2;mi++)
    #pragma unroll
    for(int pi=0;pi<2;pi++) acc[mi][pi]=(f32x4){0.f,0.f,0.f,0.f};
  for(int i=0;i<18;i++){
    int ks = wv + 4*i;
    int k0 = ks*32;
    int tap = k0>>8;
    int ky = tap/3, kx = tap%3;
    int chb = (k0&255) + q*8;
    bf16x8 a0 = *(const bf16x8*)(wp + ((size_t)(0*72+ks)*64 + l)*8);
    bf16x8 a1 = *(const bf16x8*)(wp + ((size_t)(1*72+ks)*64 + l)*8);
    int y = hh + (ky-1)*DIL;
    bf16x8 bfr[2];
    #pragma unroll
    for(int pi=0;pi<2;pi++){
      int x = w0 + pi*16 + (l&15) + (kx-1)*DIL;
      bf16x8 v = {0,0,0,0,0,0,0,0};
      if((unsigned)y<HDIM && (unsigned)x<WDIM)
        v = *(const bf16x8*)(xb + ((size_t)y*WDIM + x)*CDIM + chb);
      bfr[pi]=v;
    }
    #pragma unroll
    for(int pi=0;pi<2;pi++){
      acc[0][pi]=__builtin_amdgcn_mfma_f32_16x16x32_bf16(a0,bfr[pi],acc[0][pi],0,0,0);
      acc[1][pi]=__builtin_amdgcn_mfma_f32_16x16x32_bf16(a1,bfr[pi],acc[1][pi],0,0,0);
    }
  }
  #pragma unroll
  for(int mi=0;mi<2;mi++)
    #pragma unroll
    for(int pi=0;pi<2;pi++){
      float* pp = &part[(((wv*2+mi)*2+pi)*64 + l)*4];
      pp[0]=acc[mi][pi].x; pp[1]=acc[mi][pi].y; pp[2]=acc[mi][pi].z; pp[3]=acc[mi][pi].w;
    }
  __syncthreads();
  if(wv==0){
    #pragma unroll
    for(int mi=0;mi<2;mi++)
      #pragma unroll
      for(int pi=0;pi<2;pi++)
        #pragma unroll
        for(int r=0;r<4;r++){
          int oc = mi*16 + q*4 + r;
          if(oc<18){
            float s=0.f;
            #pragma unroll
            for(int ww=0;ww<4;ww++) s += part[(((ww*2+mi)*2+pi)*64+l)*4 + r];
            off[(size_t)(p0 + pi*16 + (l&15))*18 + oc] = s;
          }
        }
  }
}

// ---------------- 1x1 conv via MFMA: acc[pix][oc] = conv_w . x^T + b ----------------
__global__ __launch_bounds__(256) void k_conv1x1(const unsigned short* __restrict__ xtb,
    const unsigned short* __restrict__ cwp, const float* __restrict__ cb,
    float* __restrict__ acc){
  __shared__ float sacc[32*260];   // padded to kill bank conflicts
  int t=threadIdx.x, l=t&63, wv=t>>6, q=l>>4;
  size_t p0=(size_t)blockIdx.x*32;
  f32x4 c[4][2];
  #pragma unroll
  for(int ci=0;ci<4;ci++)
    #pragma unroll
    for(int pi=0;pi<2;pi++) c[ci][pi]=(f32x4){0.f,0.f,0.f,0.f};
  for(int ks=0;ks<8;ks++){
    bf16x8 bfr[2];
    #pragma unroll
    for(int pi=0;pi<2;pi++)
      bfr[pi] = *(const bf16x8*)(xtb + (p0 + pi*16 + (l&15))*CDIM + ks*32 + q*8);
    #pragma unroll
    for(int ci=0;ci<4;ci++){
      int J = wv*4+ci;
      bf16x8 a = *(const bf16x8*)(cwp + ((size_t)(J*8+ks)*64+l)*8);
      #pragma unroll
      for(int pi=0;pi<2;pi++)
        c[ci][pi]=__builtin_amdgcn_mfma_f32_16x16x32_bf16(a,bfr[pi],c[ci][pi],0,0,0);
    }
  }
  #pragma unroll
  for(int ci=0;ci<4;ci++){
    int ocb = (wv*4+ci)*16 + q*4;
    float4 bb = *(const float4*)&cb[ocb];
    #pragma unroll
    for(int pi=0;pi<2;pi++){
      int pix = pi*16+(l&15);
      sacc[pix*260 + ocb+0] = c[ci][pi].x + bb.x;
      sacc[pix*260 + ocb+1] = c[ci][pi].y + bb.y;
      sacc[pix*260 + ocb+2] = c[ci][pi].z + bb.z;
      sacc[pix*260 + ocb+3] = c[ci][pi].w + bb.w;
    }
  }
  __syncthreads();
  for(int i=0;i<32;i++) acc[(p0+i)*CDIM + t] = sacc[i*260 + t];
}

// ------- fused 3-branch deformable depthwise 3x3 + LN + GELU, acc += ... -------
__global__ __launch_bounds__(256) void k_deform3(const unsigned short* __restrict__ xtb,
    const float* __restrict__ off0, const float* __restrict__ off1, const float* __restrict__ off2,
    const float* __restrict__ dw0, const float* __restrict__ dw1, const float* __restrict__ dw2,
    const float* __restrict__ lw0, const float* __restrict__ lb0,
    const float* __restrict__ lw1, const float* __restrict__ lb1,
    const float* __restrict__ lw2, const float* __restrict__ lb2,
    float* __restrict__ acc){
  __shared__ float offs[3][18];
  __shared__ float red[3][2][4];
  int t=threadIdx.x, lane=t&63, wid=t>>6;
  float wk[3][9];
  #pragma unroll
  for(int k=0;k<9;k++){ wk[0][k]=dw0[t*9+k]; wk[1][k]=dw1[t*9+k]; wk[2][k]=dw2[t*9+k]; }
  float lwv[3]={lw0[t],lw1[t],lw2[t]};
  float lbv[3]={lb0[t],lb1[t],lb2[t]};
  for(int px=0;px<8;px++){
    size_t gp = (size_t)blockIdx.x*8 + px;
    int b=(int)(gp>>14); int p=(int)(gp&(HW-1)); int hh=p>>7, ww=p&(WDIM-1);
    if(t<18){ offs[0][t]=off0[gp*18+t]; offs[1][t]=off1[gp*18+t]; offs[2][t]=off2[gp*18+t]; }
    __syncthreads();
    const unsigned short* xb = xtb + (size_t)b*HW*CDIM;
    float d[3]={0.f,0.f,0.f};
    const int DILS[3]={1,9,12};
    #pragma unroll
    for(int j=0;j<3;j++){
      const int DIL=DILS[j];
      #pragma unroll
      for(int k=0;k<9;k++){
        float py=(float)(hh+(k/3-1)*DIL)+offs[j][2*k];
        float pxx=(float)(ww+(k%3-1)*DIL)+offs[j][2*k+1];
        float y0=floorf(py), x0=floorf(pxx);
        float fy=py-y0, fx=pxx-x0;
        int iy=(int)y0, ix=(int)x0;
        float s=0.f;
        #pragma unroll
        for(int dy=0;dy<2;++dy){
          int yy=iy+dy;
          float wy = dy? fy : 1.f-fy;
          if((unsigned)yy<HDIM){
            #pragma unroll
            for(int dx=0;dx<2;++dx){
              int xx=ix+dx;
              float wgt=wy*(dx? fx : 1.f-fx);
              if((unsigned)xx<WDIM)
                s=fmaf(wgt, bf2f(xb[((size_t)yy*WDIM+xx)*CDIM+t]), s);
            }
          }
        }
        d[j]=fmaf(wk[j][k], s, d[j]);
      }
    }
    float s0=d[0],s1=d[1],s2=d[2];
    float q0=d[0]*d[0],q1=d[1]*d[1],q2=d[2]*d[2];
    #pragma unroll
    for(int m=1;m<64;m<<=1){
      s0+=__shfl_xor(s0,m); s1+=__shfl_xor(s1,m); s2+=__shfl_xor(s2,m);
      q0+=__shfl_xor(q0,m); q1+=__shfl_xor(q1,m); q2+=__shfl_xor(q2,m);
    }
    if(lane==0){
      red[0][0][wid]=s0; red[0][1][wid]=q0;
      red[1][0][wid]=s1; red[1][1][wid]=q1;
      red[2][0][wid]=s2; red[2][1][wid]=q2;
    }
    __syncthreads();
    float r3=0.f;
    #pragma unroll
    for(int j=0;j<3;j++){
      float S=red[j][0][0]+red[j][0][1]+red[j][0][2]+red[j][0][3];
      float Q=red[j][1][0]+red[j][1][1]+red[j][1][2]+red[j][1][3];
      float u=S*(1.f/CDIM);
      float var=Q*(1.f/CDIM)-u*u;
      float xn=(d[j]-u)*rsqrtf(var+1e-6f);
      r3 += geluf(lwv[j]*xn+lbv[j]);
    }
    acc[gp*CDIM+t] += r3;
    __syncthreads();
  }
}

// ------- fused LN1 + MLP(256->512 gelu ->256, MFMA) + residual + LN2 + NCHW -------
__global__ __launch_bounds__(256) void k_mlp(const float* __restrict__ acc,
    const unsigned short* __restrict__ w1p, const float* __restrict__ b1,
    const unsigned short* __restrict__ w2p, const float* __restrict__ b2,
    const float* __restrict__ n1w, const float* __restrict__ n1b,
    const float* __restrict__ n2w, const float* __restrict__ n2b,
    float* __restrict__ dout){
  __shared__ unsigned short xbf[32*256];  // 16KB, xor-swizzled groups of 8
  __shared__ unsigned short hbf[32*512];  // 32KB, xor-swizzled
  __shared__ float redS[4*32], redQ[4*32];
  int t=threadIdx.x, l=t&63, wv=t>>6, q=l>>4;
  size_t p0=(size_t)blockIdx.x*32;
  // ---- LN1 (fp32 stats) + bf16 pack into swizzled LDS
  {
    int p=t>>3, i=t&7;
    const float* ar = acc + (p0+p)*CDIM + i*32;
    float v[32];
    float s=0.f, sq=0.f;
    #pragma unroll
    for(int j=0;j<32;j+=4){
      float4 x4 = *(const float4*)&ar[j];
      v[j]=x4.x; v[j+1]=x4.y; v[j+2]=x4.z; v[j+3]=x4.w;
      s += x4.x+x4.y+x4.z+x4.w;
      sq += x4.x*x4.x+x4.y*x4.y+x4.z*x4.z+x4.w*x4.w;
    }
    #pragma unroll
    for(int m=1;m<8;m<<=1){ s += __shfl_xor(s,m); sq += __shfl_xor(sq,m); }
    float u=s*(1.f/CDIM), var=sq*(1.f/CDIM)-u*u, rs=rsqrtf(var+1e-6f);
    #pragma unroll
    for(int g4=0; g4<4; ++g4){
      bf16x8 vec;
      #pragma unroll
      for(int e=0;e<8;e++){
        int c=i*32+g4*8+e;
        float y=(v[g4*8+e]-u)*rs*n1w[c]+n1b[c];
        vec[e]=(short)f2bf(y);
      }
      int g = i*4 + g4;
      *(bf16x8*)&xbf[p*256 + ((g ^ (p&7))<<3)] = vec;
    }
  }
  __syncthreads();
  // ---- GEMM1: hidden[j][pix], wave wv owns j rows [wv*128, wv*128+128)
  f32x4 c1[8][2];
  #pragma unroll
  for(int ji=0;ji<8;ji++){ c1[ji][0]=(f32x4){0.f,0.f,0.f,0.f}; c1[ji][1]=(f32x4){0.f,0.f,0.f,0.f}; }
  for(int ks=0;ks<8;ks++){
    bf16x8 bx[2];
    #pragma unroll
    for(int pi=0;pi<2;pi++){
      int pix=pi*16+(l&15);
      int g=ks*4+q;
      bx[pi]=*(const bf16x8*)&xbf[pix*256 + ((g^(pix&7))<<3)];
    }
    #pragma unroll
    for(int ji=0;ji<8;ji++){
      bf16x8 a=*(const bf16x8*)(w1p + ((size_t)((wv*8+ji)*8+ks)*64+l)*8);
      c1[ji][0]=__builtin_amdgcn_mfma_f32_16x16x32_bf16(a,bx[0],c1[ji][0],0,0,0);
      c1[ji][1]=__builtin_amdgcn_mfma_f32_16x16x32_bf16(a,bx[1],c1[ji][1],0,0,0);
    }
  }
  #pragma unroll
  for(int ji=0;ji<8;ji++){
    int jb=(wv*8+ji)*16 + q*4;
    float4 bb=*(const float4*)&b1[jb];
    #pragma unroll
    for(int pi=0;pi<2;pi++){
      int pix=pi*16+(l&15);
      bf16x4 t4;
      t4[0]=(short)f2bf(geluf(c1[ji][pi].x+bb.x));
      t4[1]=(short)f2bf(geluf(c1[ji][pi].y+bb.y));
      t4[2]=(short)f2bf(geluf(c1[ji][pi].z+bb.z));
      t4[3]=(short)f2bf(geluf(c1[ji][pi].w+bb.w));
      int g=jb>>3;
      *(bf16x4*)&hbf[pix*512 + ((g^(pix&7))<<3) + (jb&7)] = t4;
    }
  }
  __syncthreads();
  // ---- GEMM2: out[ch][pix], wave wv owns ch rows [wv*64, wv*64+64)
  f32x4 c2[4][2];
  #pragma unroll
  for(int ci=0;ci<4;ci++){ c2[ci][0]=(f32x4){0.f,0.f,0.f,0.f}; c2[ci][1]=(f32x4){0.f,0.f,0.f,0.f}; }
  for(int ks=0;ks<16;ks++){
    bf16x8 bh[2];
    #pragma unroll
    for(int pi=0;pi<2;pi++){
      int pix=pi*16+(l&15);
      int g=ks*4+q;
      bh[pi]=*(const bf16x8*)&hbf[pix*512 + ((g^(pix&7))<<3)];
    }
    #pragma unroll
    for(int ci=0;ci<4;ci++){
      bf16x8 a=*(const bf16x8*)(w2p + ((size_t)((wv*4+ci)*16+ks)*64+l)*8);
      c2[ci][0]=__builtin_amdgcn_mfma_f32_16x16x32_bf16(a,bh[0],c2[ci][0],0,0,0);
      c2[ci][1]=__builtin_amdgcn_mfma_f32_16x16x32_bf16(a,bh[1],c2[ci][1],0,0,0);
    }
  }
  // ---- +b2 +residual, LN2
  float z[4][2][4];
  float sp[2]={0.f,0.f}, sqp[2]={0.f,0.f};
  #pragma unroll
  for(int ci=0;ci<4;ci++){
    int cb=(wv*4+ci)*16+q*4;
    float4 bb=*(const float4*)&b2[cb];
    int g=cb>>3;
    #pragma unroll
    for(int pi=0;pi<2;pi++){
      int pix=pi*16+(l&15);
      bf16x4 rr=*(const bf16x4*)&xbf[pix*256 + ((g^(pix&7))<<3) + (cb&7)];
      float z0=c2[ci][pi].x+bb.x+bf2f((unsigned short)rr[0]);
      float z1=c2[ci][pi].y+bb.y+bf2f((unsigned short)rr[1]);
      float z2=c2[ci][pi].z+bb.z+bf2f((unsigned short)rr[2]);
      float z3=c2[ci][pi].w+bb.w+bf2f((unsigned short)rr[3]);
      z[ci][pi][0]=z0; z[ci][pi][1]=z1; z[ci][pi][2]=z2; z[ci][pi][3]=z3;
      sp[pi]+=z0+z1+z2+z3;
      sqp[pi]+=z0*z0+z1*z1+z2*z2+z3*z3;
    }
  }
  #pragma unroll
  for(int m=16;m<64;m<<=1){
    sp[0]+=__shfl_xor(sp[0],m); sp[1]+=__shfl_xor(sp[1],m);
    sqp[0]+=__shfl_xor(sqp[0],m); sqp[1]+=__shfl_xor(sqp[1],m);
  }
  if(q==0){
    redS[wv*32 + (l&15)]=sp[0];  redS[wv*32 + 16 + (l&15)]=sp[1];
    redQ[wv*32 + (l&15)]=sqp[0]; redQ[wv*32 + 16 + (l&15)]=sqp[1];
  }
  __syncthreads();
  float u[2], rs[2];
  #pragma unroll
  for(int pi=0;pi<2;pi++){
    int pix=pi*16+(l&15);
    float S=redS[pix]+redS[32+pix]+redS[64+pix]+redS[96+pix];
    float Q=redQ[pix]+redQ[32+pix]+redQ[64+pix]+redQ[96+pix];
    u[pi]=S*(1.f/CDIM);
    rs[pi]=rsqrtf(Q*(1.f/CDIM)-u[pi]*u[pi]+1e-6f);
  }
  int bimg=(int)(p0>>14); int prow0=(int)(p0&(HW-1));
  #pragma unroll
  for(int ci=0;ci<4;ci++){
    int cb=(wv*4+ci)*16+q*4;
    float4 wv4=*(const float4*)&n2w[cb];
    float4 bv4=*(const float4*)&n2b[cb];
    #pragma unroll
    for(int pi=0;pi<2;pi++){
      int prow = prow0 + pi*16 + (l&15);
      dout[((size_t)(bimg*CDIM+cb+0))*HW + prow] = (z[ci][pi][0]-u[pi])*rs[pi]*wv4.x+bv4.x;
      dout[((size_t)(bimg*CDIM+cb+1))*HW + prow] = (z[ci][pi][1]-u[pi])*rs[pi]*wv4.y+bv4.y;
      dout[((size_t)(bimg*CDIM+cb+2))*HW + prow] = (z[ci][pi][2]-u[pi])*rs[pi]*wv4.z+bv4.z;
      dout[((size_t)(bimg*CDIM+cb+3))*HW + prow] = (z[ci][pi][3]-u[pi])*rs[pi]*wv4.w+bv4.w;
    }
  }
}

extern "C" void kernel_launch(void* const* d_in, const int* in_sizes, int n_in,
                              void* d_out, int out_size, void* d_ws, size_t ws_size,
                              hipStream_t stream){
  const float* x = (const float*)d_in[0];
  const float* off_w[3] = {(const float*)d_in[1],(const float*)d_in[5],(const float*)d_in[9]};
  const float* def_w[3] = {(const float*)d_in[2],(const float*)d_in[6],(const float*)d_in[10]};
  const float* bw[3]    = {(const float*)d_in[3],(const float*)d_in[7],(const float*)d_in[11]};
  const float* bbr[3]   = {(const float*)d_in[4],(const float*)d_in[8],(const float*)d_in[12]};
  const float* conv_w = (const float*)d_in[13];
  const float* conv_b = (const float*)d_in[14];
  const float* n1w = (const float*)d_in[15];
  const float* n1b = (const float*)d_in[16];
  const float* n2w = (const float*)d_in[17];
  const float* n2b = (const float*)d_in[18];
  const float* w1  = (const float*)d_in[19];
  const float* b1  = (const float*)d_in[20];
  const float* w2  = (const float*)d_in[21];
  const float* b2  = (const float*)d_in[22];

  unsigned short* xtb = (unsigned short*)d_ws;                       // NPIX*256 bf16
  float* acc  = (float*)(xtb + (size_t)NPIX*CDIM);                   // NPIX*256 f32
  float* off0 = acc + (size_t)NPIX*CDIM;
  float* off1 = off0 + (size_t)NPIX*18;
  float* off2 = off1 + (size_t)NPIX*18;
  unsigned short* w1p  = (unsigned short*)(off2 + (size_t)NPIX*18);  // 131072
  unsigned short* w2p  = w1p + 131072;                               // 131072
  unsigned short* cwp  = w2p + 131072;                               // 65536
  unsigned short* wop0 = cwp + 65536;                                // 73728 each
  unsigned short* wop1 = wop0 + 73728;
  unsigned short* wop2 = wop1 + 73728;

  k_transpose<<<dim3(HW/32, CDIM/32, BDIM), dim3(32,8), 0, stream>>>(x, xtb);
  k_pack_w<<<512, 256, 0, stream>>>(w1, w1p, 8, 256, 131072);
  k_pack_w<<<512, 256, 0, stream>>>(w2, w2p, 16, 512, 131072);
  k_pack_w<<<256, 256, 0, stream>>>(conv_w, cwp, 8, 256, 65536);
  k_pack_off<<<288, 256, 0, stream>>>(off_w[0], wop0);
  k_pack_off<<<288, 256, 0, stream>>>(off_w[1], wop1);
  k_pack_off<<<288, 256, 0, stream>>>(off_w[2], wop2);
  k_offconv<1> <<<NPIX/32, 256, 0, stream>>>(xtb, wop0, off0);
  k_offconv<9> <<<NPIX/32, 256, 0, stream>>>(xtb, wop1, off1);
  k_offconv<12><<<NPIX/32, 256, 0, stream>>>(xtb, wop2, off2);
  k_conv1x1<<<NPIX/32, 256, 0, stream>>>(xtb, cwp, conv_b, acc);
  k_deform3<<<NPIX/8, 256, 0, stream>>>(xtb, off0, off1, off2,
      def_w[0], def_w[1], def_w[2], bw[0], bbr[0], bw[1], bbr[1], bw[2], bbr[2], acc);
  k_mlp<<<NPIX/32, 256, 0, stream>>>(acc, w1p, b1, w2p, b2, n1w, n1b, n2w, n2b, (float*)d_out);
}